// Round 1
// baseline (1525.198 us; speedup 1.0000x reference)
//
#include <hip/hip_runtime.h>

// Problem constants (fixed by setup_inputs): img (8,3,512,1024) f32, flo (8,2,512,1024) f32
constexpr int Nn = 8;
constexpr int Cc = 3;
constexpr int Hh = 512;
constexpr int Ww = 1024;
constexpr int HW = Hh * Ww;           // 524288
constexpr int NHW = Nn * HW;          // 4194304
constexpr int NCHW = Nn * Cc * HW;    // 12582912

__device__ __forceinline__ void splat_one(float* __restrict__ imgw_n,
                                          float* __restrict__ ow_n,
                                          int ix, int iy, float wt,
                                          float i0, float i1, float i2) {
    // Reference zeroes the weight for out-of-range targets; adding 0.0f is a
    // no-op, so skipping the atomics entirely is bit-equivalent for finite img.
    if (ix < 0 || ix >= Hh || iy < 0 || iy >= Ww) return;
    int t = ix * Ww + iy;
    atomicAdd(imgw_n + t,          i0 * wt);
    atomicAdd(imgw_n + HW + t,     i1 * wt);
    atomicAdd(imgw_n + 2 * HW + t, i2 * wt);
    atomicAdd(ow_n + t, wt);
}

__global__ __launch_bounds__(256) void splat_kernel(
        const float* __restrict__ img,
        const float* __restrict__ flo,
        float* __restrict__ imgw,
        float* __restrict__ ow, int ow_batch_stride) {
    int idx = blockIdx.x * blockDim.x + threadIdx.x;
    if (idx >= NHW) return;
    int n  = idx / HW;
    int hw = idx - n * HW;
    int h  = hw / Ww;
    int w  = hw - h * Ww;

    // flo layout (N,2,H,W): plane 0 = y (indexes W axis), plane 1 = x (indexes H axis)
    float y = flo[(n * 2 + 0) * HW + hw];
    float x = flo[(n * 2 + 1) * HW + hw];

    float x1f = floorf(x), y1f = floorf(y);
    float fx = x - x1f;          // == x - x1, in [0,1)
    float fy = y - y1f;
    float gx1 = fx * fx;
    float gx2 = (fx - 1.0f) * (fx - 1.0f);
    float gy1 = fy * fy;
    float gy2 = (fy - 1.0f) * (fy - 1.0f);
    float w11 = expf(-(gx1 + gy1));
    float w12 = expf(-(gx1 + gy2));
    float w21 = expf(-(gx2 + gy1));
    float w22 = expf(-(gx2 + gy2));

    int ix1 = (int)x1f + h, ix2 = ix1 + 1;   // H-axis target
    int iy1 = (int)y1f + w, iy2 = iy1 + 1;   // W-axis target

    float i0 = img[(n * Cc + 0) * HW + hw];
    float i1 = img[(n * Cc + 1) * HW + hw];
    float i2 = img[(n * Cc + 2) * HW + hw];

    float* imgw_n = imgw + (size_t)n * Cc * HW;
    float* ow_n   = ow   + (size_t)n * ow_batch_stride;
    splat_one(imgw_n, ow_n, ix1, iy1, w11, i0, i1, i2);
    splat_one(imgw_n, ow_n, ix1, iy2, w12, i0, i1, i2);
    splat_one(imgw_n, ow_n, ix2, iy1, w21, i0, i1, i2);
    splat_one(imgw_n, ow_n, ix2, iy2, w22, i0, i1, i2);
}

// Broadcast the accumulated weights (N,H,W) into all 3 channels of the o
// output region, float4-vectorized. Safe in-place for the fallback path
// (src == dst channel 0: each thread rewrites its own value).
__global__ __launch_bounds__(256) void bcast_kernel(
        const float* __restrict__ ow, int ow_batch_stride,
        float* __restrict__ o_out) {
    int idx = blockIdx.x * blockDim.x + threadIdx.x;   // over N * HW/4
    constexpr int HW4 = HW / 4;
    if (idx >= Nn * HW4) return;
    int n = idx / HW4;
    int r = idx - n * HW4;
    const float4* src = (const float4*)(ow + (size_t)n * ow_batch_stride);
    float4 v = src[r];
    float4* dst = (float4*)(o_out + (size_t)n * Cc * HW);
    dst[r]           = v;
    dst[HW4 + r]     = v;
    dst[2 * HW4 + r] = v;
}

extern "C" void kernel_launch(void* const* d_in, const int* in_sizes, int n_in,
                              void* d_out, int out_size, void* d_ws, size_t ws_size,
                              hipStream_t stream) {
    const float* img = (const float*)d_in[0];
    const float* flo = (const float*)d_in[1];
    float* out   = (float*)d_out;
    float* imgw  = out;            // first output: (N,C,H,W)
    float* o_out = out + NCHW;     // second output: (N,C,H,W)

    const size_t ow_bytes = (size_t)NHW * sizeof(float);
    const bool use_ws = ws_size >= ow_bytes;
    float* ow;
    int ow_stride;
    if (use_ws) {
        ow = (float*)d_ws;
        ow_stride = HW;
        // zero imgw region + weight accumulator; o region fully overwritten by bcast
        hipMemsetAsync(imgw, 0, (size_t)NCHW * sizeof(float), stream);
        hipMemsetAsync(ow, 0, ow_bytes, stream);
    } else {
        // accumulate weights in channel 0 of the o output region
        ow = o_out;
        ow_stride = Cc * HW;
        hipMemsetAsync(out, 0, (size_t)out_size * sizeof(float), stream);
    }

    {
        dim3 block(256);
        dim3 grid((NHW + 255) / 256);
        splat_kernel<<<grid, block, 0, stream>>>(img, flo, imgw, ow, ow_stride);
    }
    {
        dim3 block(256);
        dim3 grid((Nn * (HW / 4) + 255) / 256);
        bcast_kernel<<<grid, block, 0, stream>>>(ow, ow_stride, o_out);
    }
}

// Round 2
// 471.250 us; speedup vs baseline: 3.2365x; 3.2365x over previous
//
#include <hip/hip_runtime.h>

// Problem constants (fixed by setup_inputs): img (8,3,512,1024) f32, flo (8,2,512,1024) f32
constexpr int Nn = 8;
constexpr int Cc = 3;
constexpr int Hh = 512;
constexpr int Ww = 1024;
constexpr int HW = Hh * Ww;           // 524288
constexpr int NCHW = Nn * Cc * HW;    // 12582912

// Tiled LDS-scatter parameters
constexpr int TH = 32;                // owned output tile height
constexpr int TW = 64;                // owned output tile width
constexpr int R  = 6;                 // halo radius: covers |flow| < 6 exactly
constexpr int RH = TH + 2 * R;        // 44 source-region height
constexpr int RW = TW + 2 * R;        // 76 source-region width
constexpr int TILE_PIX = TH * TW;     // 2048
constexpr int OCAP = 4096;            // outlier list capacity (expected count ~0)

// Each block owns one TH x TW output tile of one batch image. It processes all
// source pixels within R (chebyshev) of the tile and scatters their 4 Gaussian
// splat corners into an LDS accumulator [TH][TW][4] (ch0..2 = img, ch3 = weight)
// with LDS atomics. Corners with per-axis offset |o| <= R are guaranteed to be
// caught by their target's owning block; sources with any larger offset are
// appended to an outlier list and fixed up exactly by outlier_fix below.
__global__ __launch_bounds__(256) void splat_tiled(
        const float* __restrict__ img,
        const float* __restrict__ flo,
        float* __restrict__ out,              // imgw at out, o at out+NCHW
        int* __restrict__ ocount,
        int* __restrict__ olist,
        int ocap) {
    __shared__ float acc[TILE_PIX * 4];
    const int tid = threadIdx.x;
    #pragma unroll
    for (int i = tid; i < TILE_PIX * 4; i += 256) acc[i] = 0.0f;
    __syncthreads();

    const int tw0 = blockIdx.x * TW;
    const int th0 = blockIdx.y * TH;
    const int n   = blockIdx.z;
    const float* __restrict__ floy = flo + (size_t)(n * 2 + 0) * HW;  // indexes W axis
    const float* __restrict__ flox = flo + (size_t)(n * 2 + 1) * HW;  // indexes H axis
    const float* __restrict__ imgn = img + (size_t)(n * Cc) * HW;

    for (int i = tid; i < RH * RW; i += 256) {
        int rh = i / RW;
        int rw = i - rh * RW;
        int h = th0 - R + rh;
        int w = tw0 - R + rw;
        if (h < 0 || h >= Hh || w < 0 || w >= Ww) continue;
        int hw = h * Ww + w;

        float y = floy[hw];
        float x = flox[hw];
        float x1f = floorf(x), y1f = floorf(y);
        float fx = x - x1f, fy = y - y1f;
        float gx1 = fx * fx, gx2 = (fx - 1.0f) * (fx - 1.0f);
        float gy1 = fy * fy, gy2 = (fy - 1.0f) * (fy - 1.0f);
        float w11 = __expf(-(gx1 + gy1));
        float w12 = __expf(-(gx1 + gy2));
        float w21 = __expf(-(gx2 + gy1));
        float w22 = __expf(-(gx2 + gy2));

        int lh1 = (int)x1f + h - th0;   // local tile row of corner x1
        int lh2 = lh1 + 1;
        int lw1 = (int)y1f + w - tw0;   // local tile col of corner y1
        int lw2 = lw1 + 1;

        float i0 = imgn[hw];
        float i1 = imgn[HW + hw];
        float i2 = imgn[2 * HW + hw];

        auto corner = [&](int lh, int lw, float wt) {
            if (lh >= 0 && lh < TH && lw >= 0 && lw < TW) {
                float* p = &acc[(lh * TW + lw) * 4];
                atomicAdd(p + 0, i0 * wt);
                atomicAdd(p + 1, i1 * wt);
                atomicAdd(p + 2, i2 * wt);
                atomicAdd(p + 3, wt);
            }
        };
        corner(lh1, lw1, w11);
        corner(lh1, lw2, w12);
        corner(lh2, lw1, w21);
        corner(lh2, lw2, w22);

        // Outlier detection: only when this source is in the block's OWNED
        // interior (each source belongs to exactly one interior). A corner is
        // missed by every block iff one axis offset exceeds R, which requires
        // x >= R || x < -R (floor(x)+1 > R  <=>  x >= R; floor(x) < -R <=> x < -R)
        // or same for y. Expected occurrences for N(0,1) flow: ~0.
        if (rh >= R && rh < R + TH && rw >= R && rw < R + TW) {
            if (x >= (float)R || x < -(float)R || y >= (float)R || y < -(float)R) {
                int slot = atomicAdd(ocount, 1);
                if (slot < ocap) olist[slot] = n * HW + hw;
            }
        }
    }
    __syncthreads();

    float* __restrict__ imgw  = out;
    float* __restrict__ o_out = out + NCHW;
    for (int p = tid; p < TILE_PIX; p += 256) {
        int lh = p / TW;
        int lw = p - lh * TW;
        int hw = (th0 + lh) * Ww + (tw0 + lw);
        float4 v = *(const float4*)&acc[p * 4];
        imgw[(size_t)(n * Cc + 0) * HW + hw] = v.x;
        imgw[(size_t)(n * Cc + 1) * HW + hw] = v.y;
        imgw[(size_t)(n * Cc + 2) * HW + hw] = v.z;
        o_out[(size_t)(n * Cc + 0) * HW + hw] = v.w;
        o_out[(size_t)(n * Cc + 1) * HW + hw] = v.w;
        o_out[(size_t)(n * Cc + 2) * HW + hw] = v.w;
    }
}

// Exact fixup for corners whose per-axis offset exceeds R: add them (and only
// them) directly to the outputs with global atomics. Runs after splat_tiled.
__global__ __launch_bounds__(256) void outlier_fix(
        const float* __restrict__ img,
        const float* __restrict__ flo,
        float* __restrict__ out,
        const int* __restrict__ ocount,
        const int* __restrict__ olist,
        int ocap) {
    int cnt = *ocount;
    if (cnt > ocap) cnt = ocap;
    float* __restrict__ imgw  = out;
    float* __restrict__ o_out = out + NCHW;
    for (int j = blockIdx.x * blockDim.x + threadIdx.x; j < cnt;
         j += gridDim.x * blockDim.x) {
        int idx = olist[j];
        int n  = idx / HW;
        int hw = idx - n * HW;
        int h  = hw / Ww;
        int w  = hw - h * Ww;
        float y = flo[(size_t)(n * 2 + 0) * HW + hw];
        float x = flo[(size_t)(n * 2 + 1) * HW + hw];
        float x1f = floorf(x), y1f = floorf(y);
        float fx = x - x1f, fy = y - y1f;
        float gx1 = fx * fx, gx2 = (fx - 1.0f) * (fx - 1.0f);
        float gy1 = fy * fy, gy2 = (fy - 1.0f) * (fy - 1.0f);
        float wts[4] = { __expf(-(gx1 + gy1)), __expf(-(gx1 + gy2)),
                         __expf(-(gx2 + gy1)), __expf(-(gx2 + gy2)) };
        int oh[4], ow[4];
        oh[0] = (int)x1f;     ow[0] = (int)y1f;
        oh[1] = (int)x1f;     ow[1] = (int)y1f + 1;
        oh[2] = (int)x1f + 1; ow[2] = (int)y1f;
        oh[3] = (int)x1f + 1; ow[3] = (int)y1f + 1;
        float i0 = img[(size_t)(n * Cc + 0) * HW + hw];
        float i1 = img[(size_t)(n * Cc + 1) * HW + hw];
        float i2 = img[(size_t)(n * Cc + 2) * HW + hw];
        for (int c = 0; c < 4; ++c) {
            // only corners the tiled pass missed
            if (oh[c] >= -R && oh[c] <= R && ow[c] >= -R && ow[c] <= R) continue;
            int ix = h + oh[c];
            int iy = w + ow[c];
            if (ix < 0 || ix >= Hh || iy < 0 || iy >= Ww) continue;
            int t = ix * Ww + iy;
            float wt = wts[c];
            atomicAdd(&imgw[(size_t)(n * Cc + 0) * HW + t], i0 * wt);
            atomicAdd(&imgw[(size_t)(n * Cc + 1) * HW + t], i1 * wt);
            atomicAdd(&imgw[(size_t)(n * Cc + 2) * HW + t], i2 * wt);
            atomicAdd(&o_out[(size_t)(n * Cc + 0) * HW + t], wt);
            atomicAdd(&o_out[(size_t)(n * Cc + 1) * HW + t], wt);
            atomicAdd(&o_out[(size_t)(n * Cc + 2) * HW + t], wt);
        }
    }
}

// Fallback when d_ws is too small for the list: rescan all sources and apply
// missed corners directly (same math as outlier_fix, ~0 actual atomics).
__global__ __launch_bounds__(256) void outlier_rescan(
        const float* __restrict__ img,
        const float* __restrict__ flo,
        float* __restrict__ out) {
    int idx = blockIdx.x * blockDim.x + threadIdx.x;
    if (idx >= Nn * HW) return;
    int n  = idx / HW;
    int hw = idx - n * HW;
    float y = flo[(size_t)(n * 2 + 0) * HW + hw];
    float x = flo[(size_t)(n * 2 + 1) * HW + hw];
    if (x < (float)R && x >= -(float)R && y < (float)R && y >= -(float)R) return;
    int h = hw / Ww;
    int w = hw - h * Ww;
    float x1f = floorf(x), y1f = floorf(y);
    float fx = x - x1f, fy = y - y1f;
    float gx1 = fx * fx, gx2 = (fx - 1.0f) * (fx - 1.0f);
    float gy1 = fy * fy, gy2 = (fy - 1.0f) * (fy - 1.0f);
    float wts[4] = { __expf(-(gx1 + gy1)), __expf(-(gx1 + gy2)),
                     __expf(-(gx2 + gy1)), __expf(-(gx2 + gy2)) };
    int oh[4], ow[4];
    oh[0] = (int)x1f;     ow[0] = (int)y1f;
    oh[1] = (int)x1f;     ow[1] = (int)y1f + 1;
    oh[2] = (int)x1f + 1; ow[2] = (int)y1f;
    oh[3] = (int)x1f + 1; ow[3] = (int)y1f + 1;
    float i0 = img[(size_t)(n * Cc + 0) * HW + hw];
    float i1 = img[(size_t)(n * Cc + 1) * HW + hw];
    float i2 = img[(size_t)(n * Cc + 2) * HW + hw];
    float* imgw  = out;
    float* o_out = out + NCHW;
    for (int c = 0; c < 4; ++c) {
        if (oh[c] >= -R && oh[c] <= R && ow[c] >= -R && ow[c] <= R) continue;
        int ix = h + oh[c];
        int iy = w + ow[c];
        if (ix < 0 || ix >= Hh || iy < 0 || iy >= Ww) continue;
        int t = ix * Ww + iy;
        float wt = wts[c];
        atomicAdd(&imgw[(size_t)(n * Cc + 0) * HW + t], i0 * wt);
        atomicAdd(&imgw[(size_t)(n * Cc + 1) * HW + t], i1 * wt);
        atomicAdd(&imgw[(size_t)(n * Cc + 2) * HW + t], i2 * wt);
        atomicAdd(&o_out[(size_t)(n * Cc + 0) * HW + t], wt);
        atomicAdd(&o_out[(size_t)(n * Cc + 1) * HW + t], wt);
        atomicAdd(&o_out[(size_t)(n * Cc + 2) * HW + t], wt);
    }
}

extern "C" void kernel_launch(void* const* d_in, const int* in_sizes, int n_in,
                              void* d_out, int out_size, void* d_ws, size_t ws_size,
                              hipStream_t stream) {
    const float* img = (const float*)d_in[0];
    const float* flo = (const float*)d_in[1];
    float* out = (float*)d_out;

    const size_t list_bytes = (size_t)(OCAP + 1) * sizeof(int);
    const bool use_list = ws_size >= list_bytes;

    int* ocount = (int*)d_ws;
    int* olist  = ocount + 1;

    if (use_list) {
        hipMemsetAsync(ocount, 0, sizeof(int), stream);
    }

    dim3 block(256);
    dim3 grid(Ww / TW, Hh / TH, Nn);   // 16 x 16 x 8 = 2048 blocks
    splat_tiled<<<grid, block, 0, stream>>>(img, flo, out,
                                            use_list ? ocount : nullptr,
                                            use_list ? olist : nullptr,
                                            use_list ? OCAP : 0);

    if (use_list) {
        outlier_fix<<<4, 256, 0, stream>>>(img, flo, out, ocount, olist, OCAP);
    } else {
        outlier_rescan<<<(Nn * HW + 255) / 256, 256, 0, stream>>>(img, flo, out);
    }
}

// Round 4
// 470.728 us; speedup vs baseline: 3.2401x; 1.0011x over previous
//
#include <hip/hip_runtime.h>
#include <stdint.h>

// Problem constants (fixed by setup_inputs): img (8,3,512,1024) f32, flo (8,2,512,1024) f32
constexpr int Nn = 8;
constexpr int Cc = 3;
constexpr int Hh = 512;
constexpr int Ww = 1024;
constexpr int HW = Hh * Ww;           // 524288
constexpr int NCHW = Nn * Cc * HW;    // 12582912

// Tiled LDS-scatter parameters
constexpr int TH = 32;                // owned output tile height
constexpr int TW = 64;                // owned output tile width
constexpr int R  = 6;                 // halo radius: covers -R <= flow < R exactly
constexpr int RH = TH + 2 * R;        // 44 source-region height
constexpr int RW = TW + 2 * R;        // 76 source-region width
constexpr int TILE_PIX = TH * TW;     // 2048

// Native vector type -- __builtin_nontemporal_store rejects HIP's float4
// (a HIP_vector_type class); ext_vector_type is accepted.
typedef float fvec4 __attribute__((ext_vector_type(4)));

// Hardware LDS float atomic add. HIP's atomicAdd(float*) compiles to a CAS
// loop without -munsafe-fp-atomics (R2 evidence: 357us with VALU 5%, HBM 7%,
// LDS-conflict 0 -- all pipes idle, time hidden in flat/CAS round trips).
// Inline asm on an explicit addrspace(3) pointer guarantees ds_add_f32.
typedef __attribute__((address_space(3))) float lds_f;
__device__ __forceinline__ void ds_fadd(lds_f* p, float v) {
    asm volatile("ds_add_f32 %0, %1" :: "v"(p), "v"(v) : "memory");
}

// Each block owns one TH x TW output tile of one batch image. It processes all
// source pixels within R (chebyshev) of the tile and scatters their 4 Gaussian
// splat corners into a PLANAR LDS accumulator (4 planes of [TH][TW]: ch0..2 =
// img*w, plane 3 = weight) with hardware ds_add_f32. Planar layout => lanes
// with consecutive source columns hit consecutive banks (<=2-way, free).
// Corners with per-axis offset in [-R, R] are guaranteed caught by the target
// pixel's owning block; the rare remainder (|flow| >= R, expected ~0 for
// N(0,1) flow) is applied exactly by outlier_rescan afterwards.
__global__ __launch_bounds__(256) void splat_tiled(
        const float* __restrict__ img,
        const float* __restrict__ flo,
        float* __restrict__ out) {            // imgw at out, o at out+NCHW
    __shared__ float acc[4 * TILE_PIX];       // 32 KB
    const int tid = threadIdx.x;
    {   // vectorized zero-init: 2048 fvec4 over 256 threads = 8 iters
        fvec4* a4 = (fvec4*)acc;
        fvec4 z = {0.f, 0.f, 0.f, 0.f};
        #pragma unroll
        for (int i = 0; i < 8; ++i) a4[tid + 256 * i] = z;
    }
    __syncthreads();

    const int tw0 = blockIdx.x * TW;
    const int th0 = blockIdx.y * TH;
    const int n   = blockIdx.z;
    const float* __restrict__ floy = flo + (size_t)(n * 2 + 0) * HW;  // indexes W axis
    const float* __restrict__ flox = flo + (size_t)(n * 2 + 1) * HW;  // indexes H axis
    const float* __restrict__ imgn = img + (size_t)(n * Cc) * HW;

    lds_f* A0 = (lds_f*)acc;
    lds_f* A1 = A0 + TILE_PIX;
    lds_f* A2 = A0 + 2 * TILE_PIX;
    lds_f* A3 = A0 + 3 * TILE_PIX;

    for (int i = tid; i < RH * RW; i += 256) {
        int rh = i / RW;
        int rw = i - rh * RW;
        int h = th0 - R + rh;
        int w = tw0 - R + rw;
        if (h < 0 || h >= Hh || w < 0 || w >= Ww) continue;
        int hw = h * Ww + w;

        float y = floy[hw];
        float x = flox[hw];
        float x1f = floorf(x), y1f = floorf(y);
        float fx = x - x1f, fy = y - y1f;
        float gx1 = fx * fx, gx2 = (fx - 1.0f) * (fx - 1.0f);
        float gy1 = fy * fy, gy2 = (fy - 1.0f) * (fy - 1.0f);
        float w11 = __expf(-(gx1 + gy1));
        float w12 = __expf(-(gx1 + gy2));
        float w21 = __expf(-(gx2 + gy1));
        float w22 = __expf(-(gx2 + gy2));

        int lh1 = (int)x1f + h - th0;   // local tile row of corner x1
        int lh2 = lh1 + 1;
        int lw1 = (int)y1f + w - tw0;   // local tile col of corner y1
        int lw2 = lw1 + 1;

        float i0 = imgn[hw];
        float i1 = imgn[HW + hw];
        float i2 = imgn[2 * HW + hw];

        auto corner = [&](int lh, int lw, float wt) {
            if ((unsigned)lh < (unsigned)TH && (unsigned)lw < (unsigned)TW) {
                int pix = lh * TW + lw;
                ds_fadd(A0 + pix, i0 * wt);
                ds_fadd(A1 + pix, i1 * wt);
                ds_fadd(A2 + pix, i2 * wt);
                ds_fadd(A3 + pix, wt);
            }
        };
        corner(lh1, lw1, w11);
        corner(lh1, lw2, w12);
        corner(lh2, lw1, w21);
        corner(lh2, lw2, w22);
    }
    __syncthreads();

    float* __restrict__ imgw  = out;
    float* __restrict__ o_out = out + NCHW;
    const size_t nb = (size_t)n * Cc * HW;
    const fvec4* a4 = (const fvec4*)acc;   // plane p at fvec4 index p*512
    #pragma unroll
    for (int it = 0; it < 2; ++it) {          // 512 fvec4-pixels / 256 threads
        int q = tid + 256 * it;
        fvec4 c0 = a4[q];
        fvec4 c1 = a4[512 + q];
        fvec4 c2 = a4[1024 + q];
        fvec4 wv = a4[1536 + q];
        int p0 = q * 4;
        int lh = p0 >> 6, lw = p0 & 63;
        size_t hw = (size_t)(th0 + lh) * Ww + (tw0 + lw);   // 16B aligned
        __builtin_nontemporal_store(c0, (fvec4*)(imgw + nb + hw));
        __builtin_nontemporal_store(c1, (fvec4*)(imgw + nb + HW + hw));
        __builtin_nontemporal_store(c2, (fvec4*)(imgw + nb + 2 * HW + hw));
        __builtin_nontemporal_store(wv, (fvec4*)(o_out + nb + hw));
        __builtin_nontemporal_store(wv, (fvec4*)(o_out + nb + HW + hw));
        __builtin_nontemporal_store(wv, (fvec4*)(o_out + nb + 2 * HW + hw));
    }
}

// Exact fixup for corners whose per-axis offset falls outside [-R, R]: rescan
// all sources (2 loads + early exit for ~100% of them) and apply the missed
// corners with global atomics (CAS is fine -- expected executions ~0).
// Must run after splat_tiled: its adds race with the tiles' plain stores.
__global__ __launch_bounds__(256) void outlier_rescan(
        const float* __restrict__ img,
        const float* __restrict__ flo,
        float* __restrict__ out) {
    int idx = blockIdx.x * blockDim.x + threadIdx.x;
    if (idx >= Nn * HW) return;
    int n  = idx / HW;
    int hw = idx - n * HW;
    float y = flo[(size_t)(n * 2 + 0) * HW + hw];
    float x = flo[(size_t)(n * 2 + 1) * HW + hw];
    // A corner is missed by the tiled pass iff floor(.)+1 > R or floor(.) < -R
    // on some axis  <=>  x >= R || x < -R || y >= R || y < -R.
    if (x < (float)R && x >= -(float)R && y < (float)R && y >= -(float)R) return;
    int h = hw / Ww;
    int w = hw - h * Ww;
    float x1f = floorf(x), y1f = floorf(y);
    float fx = x - x1f, fy = y - y1f;
    float gx1 = fx * fx, gx2 = (fx - 1.0f) * (fx - 1.0f);
    float gy1 = fy * fy, gy2 = (fy - 1.0f) * (fy - 1.0f);
    float wts[4] = { __expf(-(gx1 + gy1)), __expf(-(gx1 + gy2)),
                     __expf(-(gx2 + gy1)), __expf(-(gx2 + gy2)) };
    int oh[4], ow[4];
    oh[0] = (int)x1f;     ow[0] = (int)y1f;
    oh[1] = (int)x1f;     ow[1] = (int)y1f + 1;
    oh[2] = (int)x1f + 1; ow[2] = (int)y1f;
    oh[3] = (int)x1f + 1; ow[3] = (int)y1f + 1;
    float i0 = img[(size_t)(n * Cc + 0) * HW + hw];
    float i1 = img[(size_t)(n * Cc + 1) * HW + hw];
    float i2 = img[(size_t)(n * Cc + 2) * HW + hw];
    float* imgw  = out;
    float* o_out = out + NCHW;
    for (int c = 0; c < 4; ++c) {
        // only corners the tiled pass missed
        if (oh[c] >= -R && oh[c] <= R && ow[c] >= -R && ow[c] <= R) continue;
        int ix = h + oh[c];
        int iy = w + ow[c];
        if (ix < 0 || ix >= Hh || iy < 0 || iy >= Ww) continue;
        int t = ix * Ww + iy;
        float wt = wts[c];
        atomicAdd(&imgw[(size_t)(n * Cc + 0) * HW + t], i0 * wt);
        atomicAdd(&imgw[(size_t)(n * Cc + 1) * HW + t], i1 * wt);
        atomicAdd(&imgw[(size_t)(n * Cc + 2) * HW + t], i2 * wt);
        atomicAdd(&o_out[(size_t)(n * Cc + 0) * HW + t], wt);
        atomicAdd(&o_out[(size_t)(n * Cc + 1) * HW + t], wt);
        atomicAdd(&o_out[(size_t)(n * Cc + 2) * HW + t], wt);
    }
}

extern "C" void kernel_launch(void* const* d_in, const int* in_sizes, int n_in,
                              void* d_out, int out_size, void* d_ws, size_t ws_size,
                              hipStream_t stream) {
    const float* img = (const float*)d_in[0];
    const float* flo = (const float*)d_in[1];
    float* out = (float*)d_out;
    (void)d_ws; (void)ws_size;

    dim3 block(256);
    dim3 grid(Ww / TW, Hh / TH, Nn);   // 16 x 16 x 8 = 2048 blocks
    splat_tiled<<<grid, block, 0, stream>>>(img, flo, out);
    outlier_rescan<<<(Nn * HW + 255) / 256, 256, 0, stream>>>(img, flo, out);
}